// Round 11
// baseline (417.579 us; speedup 1.0000x reference)
//
#include <hip/hip_runtime.h>

typedef float v4f __attribute__((ext_vector_type(4)));

// ---------------- CSR build (split kernels — known-good) ----------------

__global__ void k_hist(const int* __restrict__ dstp, int* __restrict__ deg, int E){
  int e = blockIdx.x*256 + threadIdx.x;
  if (e < E) atomicAdd(&deg[dstp[e]], 1);
}

__global__ void k_scan1(const int* __restrict__ deg, int* __restrict__ rowptr,
                        int* __restrict__ bsum, int n){
  __shared__ int s[256];
  int i = blockIdx.x*256 + threadIdx.x;
  int v = (i < n) ? deg[i] + 1 : 0;   // +1 = self loop
  s[threadIdx.x] = v;
  __syncthreads();
  for (int off = 1; off < 256; off <<= 1){
    int t = (threadIdx.x >= off) ? s[threadIdx.x - off] : 0;
    __syncthreads();
    s[threadIdx.x] += t;
    __syncthreads();
  }
  if (i < n) rowptr[i] = s[threadIdx.x] - v;   // exclusive within block
  if (threadIdx.x == 255) bsum[blockIdx.x] = s[255];
}

__global__ void k_scan2(int* bsum, int nb){
  __shared__ int s[256];
  int v = (threadIdx.x < nb) ? bsum[threadIdx.x] : 0;
  s[threadIdx.x] = v;
  __syncthreads();
  for (int off = 1; off < 256; off <<= 1){
    int t = (threadIdx.x >= off) ? s[threadIdx.x - off] : 0;
    __syncthreads();
    s[threadIdx.x] += t;
    __syncthreads();
  }
  if (threadIdx.x < nb) bsum[threadIdx.x] = s[threadIdx.x] - v;  // exclusive
}

// scan3 + scatter_init fused: finalize rowptr, seed self-loop + cursor
__global__ void k_scan3(int* rowptr, const int* __restrict__ bsum,
                        int* __restrict__ srcs, int* __restrict__ cursor,
                        int n, int total){
  int i = blockIdx.x*256 + threadIdx.x;
  if (i < n){
    int b = rowptr[i] + bsum[blockIdx.x];
    rowptr[i] = b;
    srcs[b] = i;          // self loop at segment head
    cursor[i] = b + 1;
  }
  if (i == 0) rowptr[n] = total;
}

__global__ void k_scatter(const int* __restrict__ srcp, const int* __restrict__ dstp,
                          int* __restrict__ cursor, int* __restrict__ srcs, int E){
  int e = blockIdx.x*256 + threadIdx.x;
  if (e < E){
    int p = atomicAdd(&cursor[dstp[e]], 1);
    srcs[p] = srcp[e];
  }
}

// ---------------- fp32 GEMM 128x128 tile, 8x8 micro, split W --------------
// W columns [0,NL) from Wl, [NL,N) from Wr (no packing pass needed).
// Split-half LDS layout -> 2-way bank alias (free). K%16==0, N%128==0,
// NL%4==0; M guarded.

#define GBM 128
#define GBN 128
#define GBK 16

__device__ __forceinline__ int half_perm(int j){
  return ((j >> 3) << 2) + (j & 3) + ((j & 4) ? 64 : 0);
}

__global__ __launch_bounds__(256, 2) void k_gemm128(
    const float* __restrict__ A,
    const float* __restrict__ Wl, const float* __restrict__ Wr, int NL,
    const float* __restrict__ biasL, const float* __restrict__ biasR,
    float* __restrict__ C, int M, int K, int N){
  __shared__ float As[GBK][GBM];
  __shared__ float Ws[GBK][GBN];
  int bm = blockIdx.x * GBM, bn = blockIdx.y * GBN;
  int tid = threadIdx.x;
  int tx = tid & 15, ty = tid >> 4;
  int NR = N - NL;
  float acc[8][8] = {};
  for (int k0 = 0; k0 < K; k0 += GBK){
    #pragma unroll
    for (int l = 0; l < 2; l++){
      int idx = tid + l*256;              // 0..511
      int r = idx >> 2, kq = (idx & 3) * 4;
      float4 v = make_float4(0.f, 0.f, 0.f, 0.f);
      if (bm + r < M) v = *(const float4*)(A + (size_t)(bm + r)*K + k0 + kq);
      int rp = half_perm(r);
      As[kq+0][rp] = v.x; As[kq+1][rp] = v.y; As[kq+2][rp] = v.z; As[kq+3][rp] = v.w;
      int kr = idx >> 5, wc = (idx & 31) * 4;
      int c = bn + wc;
      const float* wsrc = (c < NL) ? (Wl + (size_t)(k0 + kr)*NL + c)
                                   : (Wr + (size_t)(k0 + kr)*NR + (c - NL));
      int wp = ((wc >> 3) << 2) + ((wc & 4) ? 64 : 0);
      *(float4*)(&Ws[kr][wp]) = *(const float4*)wsrc;
    }
    __syncthreads();
    #pragma unroll
    for (int k = 0; k < GBK; k++){
      float a[8], w[8];
      *(float4*)(a)   = *(const float4*)(&As[k][ty*4]);
      *(float4*)(a+4) = *(const float4*)(&As[k][64 + ty*4]);
      *(float4*)(w)   = *(const float4*)(&Ws[k][tx*4]);
      *(float4*)(w+4) = *(const float4*)(&Ws[k][64 + tx*4]);
      #pragma unroll
      for (int i = 0; i < 8; i++)
        #pragma unroll
        for (int j = 0; j < 8; j++)
          acc[i][j] = fmaf(a[i], w[j], acc[i][j]);
    }
    __syncthreads();
  }
  #pragma unroll
  for (int i = 0; i < 8; i++){
    int r = bm + ty*8 + i;
    if (r < M){
      #pragma unroll
      for (int j4 = 0; j4 < 2; j4++){
        int cb = bn + tx*8 + j4*4;
        const float* bsrc = (cb < NL) ? (biasL + cb) : (biasR + cb - NL);
        float4 bv = *(const float4*)bsrc;
        float4 o;
        o.x = acc[i][j4*4+0] + bv.x;
        o.y = acc[i][j4*4+1] + bv.y;
        o.z = acc[i][j4*4+2] + bv.z;
        o.w = acc[i][j4*4+3] + bv.w;
        *(float4*)(C + (size_t)r*N + cb) = o;
      }
    }
  }
}

// ---------------- DPP adds (VALU pipe, no DS ops) ----------------

template<int CTRL>
__device__ __forceinline__ float dpp_add(float x){
  int t = __builtin_amdgcn_update_dpp(0, __float_as_int(x), CTRL, 0xf, 0xf, true);
  return x + __int_as_float(t);
}

// ---------------- fused GATv2 layer: 4 edges/iter, quarter-wave -----------
// One wave per (node, head). Lanes split 4 quarters x 16; quarter q = edge q,
// each lane holds float4 features (16 lanes x 4 = 64). One dwordx4 gather
// serves 4 edge rows. Index fan-out: 1 ds_bpermute. Score reduce+broadcast:
// 4 DPP adds (row_mirror, row_half_mirror, quad xor2, quad xor1) leave the
// full 16-lane sum in EVERY lane of the row -> local exp, no readlane.
// Tail = per-lane ex mask. xlr layout: [n][H*128]: xl at [h*64..), xr at
// [H*64 + h*64..).

template<int H>
__global__ __launch_bounds__(256) void k_gat_fused(
    const float* __restrict__ xlr, const int* __restrict__ rowptr,
    const int* __restrict__ srcs, const float* __restrict__ att,
    const float* __restrict__ bias, float* __restrict__ out, int n){
  int gid = blockIdx.x * blockDim.x + threadIdx.x;
  int wave = gid >> 6, lane = gid & 63;
  int nd = wave / H, h = wave % H;
  if (nd >= n) return;
  constexpr int SHIFTB = (H == 2) ? 10 : 9;     // bytes per node row
  const int q  = lane >> 4;                     // quarter 0..3
  const int fl = (lane & 15) << 2;              // feature base within head
  const int fpos = h*64 + fl;
  const unsigned foff = (unsigned)fpos * 4u;
  const char* __restrict__ xbase = (const char*)xlr;
  v4f xr = *(const v4f*)(xlr + (size_t)nd*(H*128) + H*64 + fpos);
  v4f av = *(const v4f*)(att + fpos);
  v4f acc = {0.f, 0.f, 0.f, 0.f};
  float den = 0.f;
  const int qb = q << 2;                        // bpermute byte addr offset
  int s0 = rowptr[nd], s1 = rowptr[nd+1];
  for (int base = s0; base < s1; base += 64){
    int idx = base + lane;
    int sv = (idx < s1) ? srcs[idx] : 0;        // pad lanes hold row 0 (safe)
    int cnt = min(64, s1 - base);
    auto quad = [&](int i){
      int a = __builtin_amdgcn_ds_bpermute((i << 2) + qb, sv);
      v4f xv = *(const v4f*)(xbase + (((unsigned)a << SHIFTB) + foff));
      v4f t  = xv + xr;
      v4f lt = __builtin_elementwise_max(t, t * 0.2f);   // leaky_relu 0.2
      v4f pr = lt * av;
      float p = (pr.x + pr.y) + (pr.z + pr.w);
      p = dpp_add<0x140>(p);   // row_mirror
      p = dpp_add<0x141>(p);   // row_half_mirror
      p = dpp_add<0x4E>(p);    // quad_perm [2,3,0,1]  (xor 2)
      p = dpp_add<0xB1>(p);    // quad_perm [1,0,3,2]  (xor 1)
      float ex = (i + q < cnt) ? __expf(p) : 0.f;  // bounded scores; no max
      den += ex;
      acc += xv * ex;
    };
    for (int i = 0; i < cnt; i += 8){
      quad(i);
      if (i + 4 < cnt) quad(i + 4);
    }
  }
  // combine the four quarters (per node)
  den += __shfl_xor(den, 16, 64);
  den += __shfl_xor(den, 32, 64);
  acc.x += __shfl_xor(acc.x, 16, 64); acc.x += __shfl_xor(acc.x, 32, 64);
  acc.y += __shfl_xor(acc.y, 16, 64); acc.y += __shfl_xor(acc.y, 32, 64);
  acc.z += __shfl_xor(acc.z, 16, 64); acc.z += __shfl_xor(acc.z, 32, 64);
  acc.w += __shfl_xor(acc.w, 16, 64); acc.w += __shfl_xor(acc.w, 32, 64);
  if (q == 0){
    v4f bv = *(const v4f*)(bias + fpos);
    float inv = 1.f / (den + 1e-16f);
    v4f o = acc * inv + bv;
    v4f z = {0.f, 0.f, 0.f, 0.f};
    o = __builtin_elementwise_max(o, z);
    *(v4f*)(out + (size_t)nd*(H*64) + fpos) = o;
  }
}

// ---------------- gate: relu(h2@gw1+gb1)@gw2+gb2 -> exp, fused ------------

__global__ __launch_bounds__(256) void k_gate(
    const float* __restrict__ h2, const float* __restrict__ gw1,
    const float* __restrict__ gb1, const float* __restrict__ gw2,
    const float* __restrict__ gb2, float* __restrict__ exn, int M){
  __shared__ float As[32][64 + 4];
  __shared__ float Ws[32][64];
  int bm = blockIdx.x * 64;
  int tid = threadIdx.x;
  int tx = tid & 15, ty = tid >> 4;
  float acc[4][4] = {};
  for (int k0 = 0; k0 < 64; k0 += 32){
    #pragma unroll
    for (int l = 0; l < 2; l++){
      int idx = tid + l*256;
      int r = idx >> 3, c4 = (idx & 7) * 4;
      float4 v = make_float4(0.f, 0.f, 0.f, 0.f);
      if (bm + r < M) v = *(const float4*)(h2 + (size_t)(bm + r)*64 + k0 + c4);
      As[c4+0][r] = v.x; As[c4+1][r] = v.y; As[c4+2][r] = v.z; As[c4+3][r] = v.w;
      int kr = idx >> 4, wc4 = (idx & 15) * 4;
      *(float4*)(&Ws[kr][wc4]) = *(const float4*)(gw1 + (size_t)(k0 + kr)*64 + wc4);
    }
    __syncthreads();
    #pragma unroll
    for (int k = 0; k < 32; k++){
      float4 a4 = *(const float4*)(&As[k][ty*4]);
      float4 w4 = *(const float4*)(&Ws[k][tx*4]);
      float av[4] = {a4.x, a4.y, a4.z, a4.w};
      float wv[4] = {w4.x, w4.y, w4.z, w4.w};
      #pragma unroll
      for (int i = 0; i < 4; i++)
        #pragma unroll
        for (int j = 0; j < 4; j++)
          acc[i][j] = fmaf(av[i], wv[j], acc[i][j]);
    }
    __syncthreads();
  }
  float4 b4 = *(const float4*)(gb1 + tx*4);
  float4 w2 = *(const float4*)(gw2 + tx*4);
  float gb2v = gb2[0];
  #pragma unroll
  for (int i = 0; i < 4; i++){
    float p = fmaxf(acc[i][0] + b4.x, 0.f) * w2.x;
    p = fmaf(fmaxf(acc[i][1] + b4.y, 0.f), w2.y, p);
    p = fmaf(fmaxf(acc[i][2] + b4.z, 0.f), w2.z, p);
    p = fmaf(fmaxf(acc[i][3] + b4.w, 0.f), w2.w, p);
    p = dpp_add<0x111>(p);
    p = dpp_add<0x112>(p);
    p = dpp_add<0x114>(p);
    p = dpp_add<0x118>(p);     // lane tx==15 holds the 16-lane row sum
    if (tx == 15){
      int r = bm + ty*4 + i;
      if (r < M) exn[r] = __expf(p + gb2v);
    }
  }
}

// ---------------- pool + MLP head: one block per batch segment ----------------

__global__ __launch_bounds__(1024) void k_pool_mlp(
    const float* __restrict__ h2, const float* __restrict__ exn,
    const int* __restrict__ batch, int n,
    const float* __restrict__ l1w, const float* __restrict__ l1b,
    const float* __restrict__ l2w, const float* __restrict__ l2b,
    float* __restrict__ out){
  __shared__ float accs[16][64];
  __shared__ float dens[16];
  int b = blockIdx.x;
  int tid = threadIdx.x, lane = tid & 63, wv = tid >> 6;
  int lo = 0, hi = n;
  while (lo < hi){ int m = (lo + hi) >> 1; if (batch[m] < b) lo = m + 1; else hi = m; }
  int start = lo;
  hi = n;
  while (lo < hi){ int m = (lo + hi) >> 1; if (batch[m] < b + 1) lo = m + 1; else hi = m; }
  int end = lo;
  float acc = 0.f, den = 0.f;
  for (int nd = start + wv; nd < end; nd += 16){
    float ex = exn[nd];
    den += ex;
    acc = fmaf(ex, h2[(size_t)nd*64 + lane], acc);
  }
  accs[wv][lane] = acc;
  if (lane == 0) dens[wv] = den;
  __syncthreads();
  if (wv == 0){
    float p = 0.f, d = 0.f;
    #pragma unroll
    for (int w = 0; w < 16; w++){ p += accs[w][lane]; d += dens[w]; }
    p = p / (d + 1e-16f);
    float t = l1b[lane];
    #pragma unroll
    for (int k = 0; k < 64; k++)
      t = fmaf(__shfl(p, k, 64), l1w[k*64 + lane], t);
    t = fmaxf(t, 0.f) * l2w[lane];
    #pragma unroll
    for (int off = 32; off; off >>= 1) t += __shfl_xor(t, off, 64);
    if (lane == 0) out[b] = t + l2b[0];
  }
}

// ---------------- launch ----------------

extern "C" void kernel_launch(void* const* d_in, const int* in_sizes, int n_in,
                              void* d_out, int out_size, void* d_ws, size_t ws_size,
                              hipStream_t stream){
  const float* x    = (const float*)d_in[0];
  const int*   ei   = (const int*)  d_in[1];
  const int*   batch= (const int*)  d_in[2];
  const float* w1_l = (const float*)d_in[3];  const float* b1_l = (const float*)d_in[4];
  const float* w1_r = (const float*)d_in[5];  const float* b1_r = (const float*)d_in[6];
  const float* att1 = (const float*)d_in[7];  const float* bias1= (const float*)d_in[8];
  const float* w2_l = (const float*)d_in[9];  const float* b2_l = (const float*)d_in[10];
  const float* w2_r = (const float*)d_in[11]; const float* b2_r = (const float*)d_in[12];
  const float* att2 = (const float*)d_in[13]; const float* bias2= (const float*)d_in[14];
  const float* gw1  = (const float*)d_in[15]; const float* gb1  = (const float*)d_in[16];
  const float* gw2  = (const float*)d_in[17]; const float* gb2  = (const float*)d_in[18];
  const float* l1w  = (const float*)d_in[19]; const float* l1b  = (const float*)d_in[20];
  const float* l2w  = (const float*)d_in[21]; const float* l2b  = (const float*)d_in[22];

  const int n = in_sizes[0] / 128;
  const int E = in_sizes[1] / 2;
  const int Bb = out_size;
  const int Etot = E + n;
  const int* srcp = ei;
  const int* dstp = ei + E;

  char* wsbase = (char*)d_ws;
  size_t off = 0;
  auto alloc = [&](size_t bytes)->char*{
    char* p = wsbase + off;
    off = (off + bytes + 255) & ~(size_t)255;
    return p;
  };
  int*   deg    = (int*)  alloc((size_t)n*4);
  int*   rowptr = (int*)  alloc((size_t)(n+1)*4);
  int*   cursor = (int*)  alloc((size_t)n*4);
  int*   bsum   = (int*)  alloc(1024);
  int*   srcs   = (int*)  alloc((size_t)Etot*4);
  float* big    = (float*)alloc((size_t)n*256*4);  // xlr1; later xlr2 + h2
  float* h1     = (float*)alloc((size_t)n*128*4);  // h1; later exn
  float* xlr1 = big;
  float* xlr2 = big;
  float* h2   = big + (size_t)n*128;
  float* exn  = h1;                     // reuse after layer-2 gemm consumed h1

  int nb = (n + 255) / 256;
  int eb = (E + 255) / 256;

  // CSR build
  hipMemsetAsync(deg, 0, (size_t)n*4, stream);
  k_hist<<<eb, 256, 0, stream>>>(dstp, deg, E);
  k_scan1<<<nb, 256, 0, stream>>>(deg, rowptr, bsum, n);
  k_scan2<<<1, 256, 0, stream>>>(bsum, nb);
  k_scan3<<<nb, 256, 0, stream>>>(rowptr, bsum, srcs, cursor, n, Etot);
  k_scatter<<<eb, 256, 0, stream>>>(srcp, dstp, cursor, srcs, E);

  // layer 1 (W split: [w1_l | w1_r], no packing)
  dim3 g1((n + GBM - 1)/GBM, 256/GBN);
  k_gemm128<<<g1, 256, 0, stream>>>(x, w1_l, w1_r, 128, b1_l, b1_r, xlr1, n, 128, 256);
  long long thr1 = (long long)n * 2 * 64;
  k_gat_fused<2><<<(int)((thr1 + 255)/256), 256, 0, stream>>>(xlr1, rowptr, srcs, att1, bias1, h1, n);

  // layer 2
  dim3 g2((n + GBM - 1)/GBM, 128/GBN);
  k_gemm128<<<g2, 256, 0, stream>>>(h1, w2_l, w2_r, 64, b2_l, b2_r, xlr2, n, 128, 128);
  long long thr2 = (long long)n * 64;
  k_gat_fused<1><<<(int)((thr2 + 255)/256), 256, 0, stream>>>(xlr2, rowptr, srcs, att2, bias2, h2, n);

  // gate (gemm + gw2-dot + exp fused)
  k_gate<<<(n + 63)/64, 256, 0, stream>>>(h2, gw1, gb1, gw2, gb2, exn, n);

  // pool + MLP head
  k_pool_mlp<<<Bb, 1024, 0, stream>>>(h2, exn, batch, n, l1w, l1b, l2w, l2b, (float*)d_out);
}